// Round 1
// baseline (747.271 us; speedup 1.0000x reference)
//
#include <hip/hip_runtime.h>
#include <math.h>

#define N_ENT  50000
#define N_REL  200
#define N_EDGE 1000000

// ---- ws byte offsets ----
// 0    : int  is64 flag
// 64   : uint gmax (order-encoded float, atomicMax)
// 128  : double zsum
// 192  : float zmid
#define WS_A      256       // float a[64]  (en_w^T @ u[:64])
#define WS_B      512       // float b[64]  (en_w^T @ u[128:192])
#define WS_COUNTS 1024      // int[N_ENT]
#define WS_OFFS   262144    // int[N_ENT+1]
#define WS_CURSOR 524288    // int[N_ENT]
#define WS_ZSRC   786432    // float[N_ENT]
#define WS_ZDST   1048576   // float[N_ENT]
#define WS_EDST   2097152   // int[N_EDGE]
#define WS_EATT   6291456   // float[N_EDGE]
#define WS_BUFA   12582912  // float[N_ENT*64]   (~25.4 MB total ws use)

__device__ __forceinline__ int ld_tri(const void* t, int i, int is64) {
  return is64 ? (int)((const long long*)t)[i] : ((const int*)t)[i];
}

// order-preserving float<->uint encoding for atomicMax
__device__ __forceinline__ unsigned fenc(float f) {
  unsigned u = __float_as_uint(f);
  return (u & 0x80000000u) ? ~u : (u | 0x80000000u);
}
__device__ __forceinline__ float fdec(unsigned u) {
  unsigned v = (u & 0x80000000u) ? (u & 0x7fffffffu) : ~u;
  return __uint_as_float(v);
}

__global__ void k_init(const void* tri, int* counts, int* misc, unsigned* gmax, double* zsum) {
  int i = blockIdx.x * blockDim.x + threadIdx.x;
  if (i < N_ENT) counts[i] = 0;
  if (i == 0) {
    // detect int64 vs int32 triples: int64 (values < 2^31) => all odd int32 words zero
    const int* t32 = (const int*)tri;
    int allz = 1;
    for (int k = 1; k < 256; k += 2) allz &= (t32[k] == 0);
    misc[0] = allz;
    *gmax = 0u;       // below fenc(any finite float)
    *zsum = 0.0;
  }
}

__global__ void k_hist(const void* tri, int* counts, const int* misc) {
  int is64 = misc[0];
  int stride = gridDim.x * blockDim.x;
  for (int e = blockIdx.x * blockDim.x + threadIdx.x; e < N_EDGE; e += stride) {
    int s = ld_tri(tri, 3 * e, is64);
    atomicAdd(&counts[s], 1);
  }
}

__global__ void k_scan(const int* counts, int* offs, int* cursor) {
  __shared__ int part[1024];
  const int C = 49;  // 1024*49 = 50176 >= N_ENT
  int t = threadIdx.x;
  int lo = t * C;
  int hi = lo + C; if (hi > N_ENT) hi = N_ENT; if (lo > N_ENT) lo = N_ENT;
  int s = 0;
  for (int i = lo; i < hi; i++) s += counts[i];
  part[t] = s;
  __syncthreads();
  for (int d = 1; d < 1024; d <<= 1) {
    int v = (t >= d) ? part[t - d] : 0;
    __syncthreads();
    part[t] += v;
    __syncthreads();
  }
  int base = (t == 0) ? 0 : part[t - 1];
  for (int i = lo; i < hi; i++) {
    offs[i] = base; cursor[i] = base;
    base += counts[i];
  }
  if (t == 0) offs[N_ENT] = part[1023];
}

__global__ void k_scatter(const void* tri, const float* re_att, int* cursor,
                          int* edst, float* eatt, const int* misc) {
  int is64 = misc[0];
  int stride = gridDim.x * blockDim.x;
  for (int e = blockIdx.x * blockDim.x + threadIdx.x; e < N_EDGE; e += stride) {
    int s = ld_tri(tri, 3 * e + 0, is64);
    int r = ld_tri(tri, 3 * e + 1, is64);
    int d = ld_tri(tri, 3 * e + 2, is64);
    int p = atomicAdd(&cursor[s], 1);
    edst[p] = d;
    eatt[p] = re_att[r];
  }
}

// a[k] = sum_j u[j]*en_w[j][k];  b[k] = sum_j u[128+j]*en_w[j][k];
// zmid = sum_j u[64+j] * (re_weight[j,:] . re_spec)
__global__ void k_pre(const float* u, const float* enw, const float* rew, const float* rsp,
                      float* a, float* b, float* zmid) {
  int k = threadIdx.x;  // 64 threads
  float aa = 0.f, bb = 0.f;
  for (int j = 0; j < 64; j++) {
    float w = enw[j * 64 + k];
    aa += u[j] * w;
    bb += u[128 + j] * w;
  }
  a[k] = aa; b[k] = bb;
  float t = 0.f;
  for (int c = 0; c < 64; c++) t += rew[k * 64 + c] * rsp[c];
  t *= u[64 + k];
  for (int o = 32; o; o >>= 1) t += __shfl_down(t, o);
  if (k == 0) *zmid = t;
}

// One wave per node: msg accumulate (CSR) + self, then (v @ W) via LDS broadcast, tanh.
// EPI: also reduce z_src[i]=y.a, z_dst[i]=y.b
template <int EPI>
__global__ void k_wgc(const float* __restrict__ x, const float* __restrict__ W,
                      const int* __restrict__ offs, const int* __restrict__ edst,
                      const float* __restrict__ eatt, float* __restrict__ y,
                      const float* __restrict__ a, const float* __restrict__ b,
                      float* __restrict__ zsrc, float* __restrict__ zdst) {
  __shared__ float sv[4][64];
  int wave = threadIdx.x >> 6;
  int lane = threadIdx.x & 63;
  int node = blockIdx.x * 4 + wave;
  float m = 0.f;
  if (node < N_ENT) {
    int e0 = offs[node], e1 = offs[node + 1];
    for (int e = e0; e < e1; e++) {
      int d = edst[e];
      float att = eatt[e];
      m += att * x[(size_t)d * 64 + lane];
    }
    m += x[(size_t)node * 64 + lane];
  }
  sv[wave][lane] = m;
  __syncthreads();
  if (node < N_ENT) {
    float acc = 0.f;
    for (int k = 0; k < 64; k++) acc += sv[wave][k] * W[k * 64 + lane];
    float yv = tanhf(acc);
    y[(size_t)node * 64 + lane] = yv;
    if (EPI) {
      float za = yv * a[lane], zb = yv * b[lane];
      for (int o = 32; o; o >>= 1) { za += __shfl_down(za, o); zb += __shfl_down(zb, o); }
      if (lane == 0) { zsrc[node] = za; zdst[node] = zb; }
    }
  }
}

__global__ void k_smax(const void* tri, const float* zs, const float* zd, const float* zmid,
                       unsigned* gmax, const int* misc) {
  int is64 = misc[0];
  float zm = *zmid;
  float mx = -3.4e38f;
  int stride = gridDim.x * blockDim.x;
  for (int e = blockIdx.x * blockDim.x + threadIdx.x; e < N_EDGE; e += stride) {
    int s = ld_tri(tri, 3 * e + 0, is64);
    int d = ld_tri(tri, 3 * e + 2, is64);
    float sc = zs[s] + zm + zd[d];
    sc = sc >= 0.f ? sc : 0.01f * sc;
    mx = fmaxf(mx, sc);
  }
  for (int o = 32; o; o >>= 1) mx = fmaxf(mx, __shfl_down(mx, o));
  __shared__ float wm[4];
  if ((threadIdx.x & 63) == 0) wm[threadIdx.x >> 6] = mx;
  __syncthreads();
  if (threadIdx.x == 0) {
    float m = fmaxf(fmaxf(wm[0], wm[1]), fmaxf(wm[2], wm[3]));
    atomicMax(gmax, fenc(m));
  }
}

__global__ void k_ssum(const void* tri, const float* zs, const float* zd, const float* zmid,
                       const unsigned* gmax, double* zsum, const int* misc) {
  int is64 = misc[0];
  float zm = *zmid;
  float gm = fdec(*gmax);
  float s0 = 0.f;
  int stride = gridDim.x * blockDim.x;
  for (int e = blockIdx.x * blockDim.x + threadIdx.x; e < N_EDGE; e += stride) {
    int s = ld_tri(tri, 3 * e + 0, is64);
    int d = ld_tri(tri, 3 * e + 2, is64);
    float sc = zs[s] + zm + zd[d];
    sc = sc >= 0.f ? sc : 0.01f * sc;
    s0 += expf(sc - gm);
  }
  for (int o = 32; o; o >>= 1) s0 += __shfl_down(s0, o);
  __shared__ float wsum[4];
  if ((threadIdx.x & 63) == 0) wsum[threadIdx.x >> 6] = s0;
  __syncthreads();
  if (threadIdx.x == 0) {
    atomicAdd(zsum, (double)(wsum[0] + wsum[1] + wsum[2] + wsum[3]));
  }
}

// out[i,l] = sum_{e in CSR[i]} exp(lrelu(zs[i]+zm+zd[dst_e]) - gmax)/Z * x[dst_e, l]
__global__ void k_out(const float* __restrict__ x, const int* __restrict__ offs,
                      const int* __restrict__ edst, const float* __restrict__ zs,
                      const float* __restrict__ zd, const float* zmid,
                      const unsigned* gmax, const double* zsum, float* __restrict__ out) {
  int wave = threadIdx.x >> 6;
  int lane = threadIdx.x & 63;
  int node = blockIdx.x * 4 + wave;
  if (node >= N_ENT) return;
  float zm = *zmid;
  float gm = fdec(*gmax);
  float invZ = (float)(1.0 / *zsum);
  float zi = zs[node];
  float acc = 0.f;
  int e0 = offs[node], e1 = offs[node + 1];
  for (int e = e0; e < e1; e++) {
    int d = edst[e];
    float sc = zi + zm + zd[d];
    sc = sc >= 0.f ? sc : 0.01f * sc;
    float al = expf(sc - gm) * invZ;
    acc += al * x[(size_t)d * 64 + lane];
  }
  out[(size_t)node * 64 + lane] = acc;
}

extern "C" void kernel_launch(void* const* d_in, const int* in_sizes, int n_in,
                              void* d_out, int out_size, void* d_ws, size_t ws_size,
                              hipStream_t stream) {
  const float* emb   = (const float*)d_in[0];
  const float* reatt = (const float*)d_in[1];
  const float* W1    = (const float*)d_in[2];
  const float* W2    = (const float*)d_in[3];
  const float* W3    = (const float*)d_in[4];
  const float* u     = (const float*)d_in[5];
  const float* enw   = (const float*)d_in[6];
  const float* rew   = (const float*)d_in[7];
  const float* rsp   = (const float*)d_in[8];
  const void*  tri   = d_in[9];

  char* ws = (char*)d_ws;
  int*      misc   = (int*)(ws + 0);
  unsigned* gmax   = (unsigned*)(ws + 64);
  double*   zsum   = (double*)(ws + 128);
  float*    zmid   = (float*)(ws + 192);
  float*    a      = (float*)(ws + WS_A);
  float*    b      = (float*)(ws + WS_B);
  int*      counts = (int*)(ws + WS_COUNTS);
  int*      offs   = (int*)(ws + WS_OFFS);
  int*      cursor = (int*)(ws + WS_CURSOR);
  float*    zsrc   = (float*)(ws + WS_ZSRC);
  float*    zdst   = (float*)(ws + WS_ZDST);
  int*      edst   = (int*)(ws + WS_EDST);
  float*    eatt   = (float*)(ws + WS_EATT);
  float*    bufA   = (float*)(ws + WS_BUFA);
  float*    out    = (float*)d_out;

  k_init<<<196, 256, 0, stream>>>(tri, counts, misc, gmax, zsum);
  k_hist<<<1024, 256, 0, stream>>>(tri, counts, misc);
  k_scan<<<1, 1024, 0, stream>>>(counts, offs, cursor);
  k_scatter<<<1024, 256, 0, stream>>>(tri, reatt, cursor, edst, eatt, misc);
  k_pre<<<1, 64, 0, stream>>>(u, enw, rew, rsp, a, b, zmid);

  int nb = (N_ENT + 3) / 4;  // 4 nodes (waves) per 256-thread block
  k_wgc<0><<<nb, 256, 0, stream>>>(emb,  W1, offs, edst, eatt, bufA, nullptr, nullptr, nullptr, nullptr);
  k_wgc<0><<<nb, 256, 0, stream>>>(bufA, W2, offs, edst, eatt, out,  nullptr, nullptr, nullptr, nullptr);
  k_wgc<1><<<nb, 256, 0, stream>>>(out,  W3, offs, edst, eatt, bufA, a, b, zsrc, zdst);

  k_smax<<<1024, 256, 0, stream>>>(tri, zsrc, zdst, zmid, gmax, misc);
  k_ssum<<<1024, 256, 0, stream>>>(tri, zsrc, zdst, zmid, gmax, zsum, misc);
  k_out<<<nb, 256, 0, stream>>>(bufA, offs, edst, zsrc, zdst, zmid, gmax, zsum, out);
}

// Round 2
// 461.419 us; speedup vs baseline: 1.6195x; 1.6195x over previous
//
#include <hip/hip_runtime.h>
#include <math.h>

#define N_ENT  50000
#define N_REL  200
#define N_EDGE 1000000

// ---- ws byte offsets ----
#define WS_MISC   0          // int is64
#define WS_ZSUM   128        // double
#define WS_ZMID   192        // float
#define WS_A      256        // float[64]
#define WS_B      512        // float[64]
#define WS_COUNTS 0x00100000 // int[N_ENT]
#define WS_OFFS   0x00140000 // int[N_ENT+1]
#define WS_CURSOR 0x00180000 // int[N_ENT]
#define WS_ZSRC   0x001C0000 // float[N_ENT]
#define WS_ZDST   0x00200000 // float[N_ENT]
#define WS_SNODE  0x00240000 // float[N_ENT]
#define WS_EDST   0x00280000 // int[N_EDGE]
#define WS_EATT   0x00680000 // float[N_EDGE]
#define WS_XB0    0x00A80000 // ushort[N_ENT*64] bf16
#define WS_XB1    0x01100000 // ushort[N_ENT*64] bf16  (ends ~24.6MB)

__device__ __forceinline__ int ld_tri(const void* t, int i, int is64) {
  return is64 ? (int)((const long long*)t)[i] : ((const int*)t)[i];
}
__device__ __forceinline__ float bf2f(unsigned short u) {
  return __uint_as_float(((unsigned)u) << 16);
}
__device__ __forceinline__ unsigned short f2bf(float f) {  // RNE
  unsigned u = __float_as_uint(f);
  unsigned r = ((u >> 16) & 1u) + 0x7fffu;
  return (unsigned short)((u + r) >> 16);
}
__device__ __forceinline__ float lanebc(float v, int k) {
  return __uint_as_float((unsigned)__builtin_amdgcn_readlane((int)__float_as_uint(v), k));
}

__global__ void k_init(const void* tri, int* counts, int* misc, double* zsum) {
  int i = blockIdx.x * blockDim.x + threadIdx.x;
  if (i < N_ENT) counts[i] = 0;
  if (i == 0) {
    const int* t32 = (const int*)tri;
    int allz = 1;
    for (int k = 1; k < 256; k += 2) allz &= (t32[k] == 0);
    misc[0] = allz;
    *zsum = 0.0;
  }
}

// emb fp32 -> bf16 table (float4 -> 4x bf16)
__global__ void k_conv(const float* __restrict__ x, unsigned short* __restrict__ xb) {
  int i = blockIdx.x * blockDim.x + threadIdx.x;   // 800K quads
  if (i >= N_ENT * 16) return;
  float4 v = ((const float4*)x)[i];
  ushort4 o;
  o.x = f2bf(v.x); o.y = f2bf(v.y); o.z = f2bf(v.z); o.w = f2bf(v.w);
  ((ushort4*)xb)[i] = o;
}

__global__ void k_hist(const void* tri, int* counts, const int* misc) {
  int is64 = misc[0];
  int stride = gridDim.x * blockDim.x;
  for (int e = blockIdx.x * blockDim.x + threadIdx.x; e < N_EDGE; e += stride)
    atomicAdd(&counts[ld_tri(tri, 3 * e, is64)], 1);
}

__global__ void k_scan(const int* counts, int* offs, int* cursor) {
  __shared__ int part[1024];
  const int C = 49;
  int t = threadIdx.x;
  int lo = t * C, hi = lo + C;
  if (hi > N_ENT) hi = N_ENT;
  if (lo > N_ENT) lo = N_ENT;
  int s = 0;
  for (int i = lo; i < hi; i++) s += counts[i];
  part[t] = s;
  __syncthreads();
  for (int d = 1; d < 1024; d <<= 1) {
    int v = (t >= d) ? part[t - d] : 0;
    __syncthreads();
    part[t] += v;
    __syncthreads();
  }
  int base = (t == 0) ? 0 : part[t - 1];
  for (int i = lo; i < hi; i++) {
    offs[i] = base; cursor[i] = base;
    base += counts[i];
  }
  if (t == 0) offs[N_ENT] = part[1023];
}

__global__ void k_scatter(const void* tri, const float* re_att, int* cursor,
                          int* edst, float* eatt, const int* misc) {
  int is64 = misc[0];
  int stride = gridDim.x * blockDim.x;
  for (int e = blockIdx.x * blockDim.x + threadIdx.x; e < N_EDGE; e += stride) {
    int s = ld_tri(tri, 3 * e + 0, is64);
    int r = ld_tri(tri, 3 * e + 1, is64);
    int d = ld_tri(tri, 3 * e + 2, is64);
    int p = atomicAdd(&cursor[s], 1);
    edst[p] = d;
    eatt[p] = re_att[r];
  }
}

__global__ void k_pre(const float* u, const float* enw, const float* rew, const float* rsp,
                      float* a, float* b, float* zmid) {
  int k = threadIdx.x;  // 64
  float aa = 0.f, bb = 0.f;
  for (int j = 0; j < 64; j++) {
    float w = enw[j * 64 + k];
    aa += u[j] * w;
    bb += u[128 + j] * w;
  }
  a[k] = aa; b[k] = bb;
  float t = 0.f;
  for (int c = 0; c < 64; c++) t += rew[k * 64 + c] * rsp[c];
  t *= u[64 + k];
  for (int o = 32; o; o >>= 1) t += __shfl_down(t, o);
  if (k == 0) *zmid = t;
}

// one wave per node, no LDS, no inter-wave sync
template <int EPI>
__global__ void k_wgc(const unsigned short* __restrict__ xb, const float* __restrict__ W,
                      const int* __restrict__ offs, const int* __restrict__ edst,
                      const float* __restrict__ eatt, unsigned short* __restrict__ yb,
                      const float* __restrict__ a, const float* __restrict__ b,
                      float* __restrict__ zsrc, float* __restrict__ zdst) {
  int wid = (blockIdx.x * blockDim.x + threadIdx.x) >> 6;
  int lane = threadIdx.x & 63;
  if (wid >= N_ENT) return;
  int node = wid;
  int e0 = offs[node], e1 = offs[node + 1];
  float m0 = 0.f, m1 = 0.f, m2 = 0.f, m3 = 0.f;
  int e = e0;
  for (; e + 4 <= e1; e += 4) {
    int d0 = edst[e], d1 = edst[e + 1], d2 = edst[e + 2], d3 = edst[e + 3];
    float t0 = eatt[e], t1 = eatt[e + 1], t2 = eatt[e + 2], t3 = eatt[e + 3];
    m0 += t0 * bf2f(xb[d0 * 64 + lane]);
    m1 += t1 * bf2f(xb[d1 * 64 + lane]);
    m2 += t2 * bf2f(xb[d2 * 64 + lane]);
    m3 += t3 * bf2f(xb[d3 * 64 + lane]);
  }
  for (; e < e1; e++) m0 += eatt[e] * bf2f(xb[edst[e] * 64 + lane]);
  float m = (m0 + m1) + (m2 + m3) + bf2f(xb[node * 64 + lane]);
  float acc = 0.f;
#pragma unroll
  for (int k = 0; k < 64; k++) acc += lanebc(m, k) * W[k * 64 + lane];
  float yv = tanhf(acc);
  yb[node * 64 + lane] = f2bf(yv);
  if (EPI) {
    float za = yv * a[lane], zb = yv * b[lane];
    for (int o = 32; o; o >>= 1) { za += __shfl_down(za, o); zb += __shfl_down(zb, o); }
    if (lane == 0) { zsrc[node] = za; zdst[node] = zb; }
  }
}

// unnormalized attention aggregate + per-node softmax partial sums
__global__ void k_out(const unsigned short* __restrict__ xb, const int* __restrict__ offs,
                      const int* __restrict__ edst, const float* __restrict__ zs,
                      const float* __restrict__ zd, const float* zmid,
                      float* __restrict__ out, float* __restrict__ snode) {
  int wid = (blockIdx.x * blockDim.x + threadIdx.x) >> 6;
  int lane = threadIdx.x & 63;
  if (wid >= N_ENT) return;
  int node = wid;
  float zi = zs[node] + *zmid;
  float a0 = 0.f, a1 = 0.f, a2 = 0.f, a3 = 0.f;
  float s0 = 0.f;
  int e0 = offs[node], e1 = offs[node + 1];
  int e = e0;
  for (; e + 4 <= e1; e += 4) {
    int d0 = edst[e], d1 = edst[e + 1], d2 = edst[e + 2], d3 = edst[e + 3];
    float c0 = zi + zd[d0], c1 = zi + zd[d1], c2 = zi + zd[d2], c3 = zi + zd[d3];
    c0 = c0 >= 0.f ? c0 : 0.01f * c0;
    c1 = c1 >= 0.f ? c1 : 0.01f * c1;
    c2 = c2 >= 0.f ? c2 : 0.01f * c2;
    c3 = c3 >= 0.f ? c3 : 0.01f * c3;
    float w0 = expf(c0), w1 = expf(c1), w2 = expf(c2), w3 = expf(c3);
    s0 += (w0 + w1) + (w2 + w3);
    a0 += w0 * bf2f(xb[d0 * 64 + lane]);
    a1 += w1 * bf2f(xb[d1 * 64 + lane]);
    a2 += w2 * bf2f(xb[d2 * 64 + lane]);
    a3 += w3 * bf2f(xb[d3 * 64 + lane]);
  }
  for (; e < e1; e++) {
    int d = edst[e];
    float c = zi + zd[d];
    c = c >= 0.f ? c : 0.01f * c;
    float w = expf(c);
    s0 += w;
    a0 += w * bf2f(xb[d * 64 + lane]);
  }
  out[(size_t)node * 64 + lane] = (a0 + a1) + (a2 + a3);
  if (lane == 0) snode[node] = s0;
}

__global__ void k_red(const float* __restrict__ snode, double* zsum) {
  int stride = gridDim.x * blockDim.x;
  double s = 0.0;
  for (int i = blockIdx.x * blockDim.x + threadIdx.x; i < N_ENT; i += stride)
    s += (double)snode[i];
  for (int o = 32; o; o >>= 1) s += __shfl_down(s, o);
  __shared__ double ws_[4];
  if ((threadIdx.x & 63) == 0) ws_[threadIdx.x >> 6] = s;
  __syncthreads();
  if (threadIdx.x == 0)
    atomicAdd(zsum, ws_[0] + ws_[1] + ws_[2] + ws_[3]);
}

__global__ void k_norm(float* __restrict__ out, const double* zsum) {
  int i = blockIdx.x * blockDim.x + threadIdx.x;  // 800K quads
  if (i >= N_ENT * 16) return;
  float invZ = (float)(1.0 / *zsum);
  float4 v = ((float4*)out)[i];
  v.x *= invZ; v.y *= invZ; v.z *= invZ; v.w *= invZ;
  ((float4*)out)[i] = v;
}

extern "C" void kernel_launch(void* const* d_in, const int* in_sizes, int n_in,
                              void* d_out, int out_size, void* d_ws, size_t ws_size,
                              hipStream_t stream) {
  const float* emb   = (const float*)d_in[0];
  const float* reatt = (const float*)d_in[1];
  const float* W1    = (const float*)d_in[2];
  const float* W2    = (const float*)d_in[3];
  const float* W3    = (const float*)d_in[4];
  const float* u     = (const float*)d_in[5];
  const float* enw   = (const float*)d_in[6];
  const float* rew   = (const float*)d_in[7];
  const float* rsp   = (const float*)d_in[8];
  const void*  tri   = d_in[9];

  char* ws = (char*)d_ws;
  int*            misc   = (int*)(ws + WS_MISC);
  double*         zsum   = (double*)(ws + WS_ZSUM);
  float*          zmid   = (float*)(ws + WS_ZMID);
  float*          a      = (float*)(ws + WS_A);
  float*          b      = (float*)(ws + WS_B);
  int*            counts = (int*)(ws + WS_COUNTS);
  int*            offs   = (int*)(ws + WS_OFFS);
  int*            cursor = (int*)(ws + WS_CURSOR);
  float*          zsrc   = (float*)(ws + WS_ZSRC);
  float*          zdst   = (float*)(ws + WS_ZDST);
  float*          snode  = (float*)(ws + WS_SNODE);
  int*            edst   = (int*)(ws + WS_EDST);
  float*          eatt   = (float*)(ws + WS_EATT);
  unsigned short* xb0    = (unsigned short*)(ws + WS_XB0);
  unsigned short* xb1    = (unsigned short*)(ws + WS_XB1);
  float*          out    = (float*)d_out;

  k_init<<<196, 256, 0, stream>>>(tri, counts, misc, zsum);
  k_conv<<<3125, 256, 0, stream>>>(emb, xb0);
  k_hist<<<1024, 256, 0, stream>>>(tri, counts, misc);
  k_scan<<<1, 1024, 0, stream>>>(counts, offs, cursor);
  k_scatter<<<1024, 256, 0, stream>>>(tri, reatt, cursor, edst, eatt, misc);
  k_pre<<<1, 64, 0, stream>>>(u, enw, rew, rsp, a, b, zmid);

  int nb = (N_ENT * 64 + 255) / 256;  // 12500: 4 independent waves / block
  k_wgc<0><<<nb, 256, 0, stream>>>(xb0, W1, offs, edst, eatt, xb1, nullptr, nullptr, nullptr, nullptr);
  k_wgc<0><<<nb, 256, 0, stream>>>(xb1, W2, offs, edst, eatt, xb0, nullptr, nullptr, nullptr, nullptr);
  k_wgc<1><<<nb, 256, 0, stream>>>(xb0, W3, offs, edst, eatt, xb1, a, b, zsrc, zdst);

  k_out<<<nb, 256, 0, stream>>>(xb1, offs, edst, zsrc, zdst, zmid, out, snode);
  k_red<<<196, 256, 0, stream>>>(snode, zsum);
  k_norm<<<3125, 256, 0, stream>>>(out, zsum);
}

// Round 4
// 299.887 us; speedup vs baseline: 2.4918x; 1.5386x over previous
//
#include <hip/hip_runtime.h>
#include <math.h>

#define N_ENT  50000
#define N_REL  200
#define N_EDGE 1000000
#define CHUNK  196   // ceil(N_ENT/256)

// ---- ws byte offsets ----
#define WS_MISC   0          // int is64
#define WS_ZSUM   128        // double
#define WS_ZMID   192        // float
#define WS_A      256        // float[64]
#define WS_B      512        // float[64]
#define WS_BSUM   0x000E0000 // int[256]
#define WS_BBASE  0x000F0000 // int[256]
#define WS_COUNTS 0x00100000 // int[N_ENT]
#define WS_OFFS   0x00140000 // int[N_ENT+1]
#define WS_CURSOR 0x00180000 // int[N_ENT]
#define WS_ZSRC   0x001C0000 // float[N_ENT]
#define WS_ZDST   0x00200000 // float[N_ENT]
#define WS_SNODE  0x00240000 // float[N_ENT]
#define WS_EPACK  0x00280000 // int2[N_EDGE] {dst, att}
#define WS_XB0    0x00A80000 // ushort[N_ENT*64] bf16
#define WS_XB1    0x01100000 // ushort[N_ENT*64] bf16

__device__ __forceinline__ int ld_tri(const void* t, int i, int is64) {
  return is64 ? (int)((const long long*)t)[i] : ((const int*)t)[i];
}
__device__ __forceinline__ float bflo(unsigned u) { return __uint_as_float(u << 16); }
__device__ __forceinline__ float bfhi(unsigned u) { return __uint_as_float(u & 0xffff0000u); }
__device__ __forceinline__ float bf2f(unsigned short u) {
  return __uint_as_float(((unsigned)u) << 16);
}
__device__ __forceinline__ unsigned short f2bf(float f) {  // RNE
  unsigned u = __float_as_uint(f);
  unsigned r = ((u >> 16) & 1u) + 0x7fffu;
  return (unsigned short)((u + r) >> 16);
}
__device__ __forceinline__ float lanebc(float v, int k) {
  return __uint_as_float((unsigned)__builtin_amdgcn_readlane((int)__float_as_uint(v), k));
}
__device__ __forceinline__ float fast_tanh(float x) {
  float ex = __expf(2.f * x);
  return 1.f - __fdividef(2.f, ex + 1.f);
}
__device__ __forceinline__ void fma8(float* acc, float wt, uint4 q) {
  acc[0] += wt * bflo(q.x); acc[1] += wt * bfhi(q.x);
  acc[2] += wt * bflo(q.y); acc[3] += wt * bfhi(q.y);
  acc[4] += wt * bflo(q.z); acc[5] += wt * bfhi(q.z);
  acc[6] += wt * bflo(q.w); acc[7] += wt * bfhi(q.w);
}

__global__ void k_init(const void* tri, int* counts, int* misc, double* zsum) {
  int i = blockIdx.x * blockDim.x + threadIdx.x;
  if (i < N_ENT) counts[i] = 0;
  if (blockIdx.x == 0 && threadIdx.x < 64) {
    int l = threadIdx.x;
    int z = ((const int*)tri)[2 * l + 1];
    unsigned long long m = __ballot(z == 0);
    if (l == 0) { misc[0] = (m == ~0ull) ? 1 : 0; *zsum = 0.0; }
  }
}

__global__ void k_conv(const float* __restrict__ x, unsigned short* __restrict__ xb) {
  int i = blockIdx.x * blockDim.x + threadIdx.x;   // 800K quads
  if (i >= N_ENT * 16) return;
  float4 v = ((const float4*)x)[i];
  ushort4 o;
  o.x = f2bf(v.x); o.y = f2bf(v.y); o.z = f2bf(v.z); o.w = f2bf(v.w);
  ((ushort4*)xb)[i] = o;
}

__global__ void k_hist(const void* tri, int* counts, const int* misc) {
  int is64 = misc[0];
  int stride = gridDim.x * blockDim.x;
  for (int e = blockIdx.x * blockDim.x + threadIdx.x; e < N_EDGE; e += stride)
    atomicAdd(&counts[ld_tri(tri, 3 * e, is64)], 1);
}

__global__ void k_scanA(const int* __restrict__ counts, int* __restrict__ bsum) {
  __shared__ int sm[4];
  int t = threadIdx.x;
  int i = blockIdx.x * CHUNK + t;
  int v = (t < CHUNK && i < N_ENT) ? counts[i] : 0;
  for (int o = 32; o; o >>= 1) v += __shfl_down(v, o);
  if ((t & 63) == 0) sm[t >> 6] = v;
  __syncthreads();
  if (t == 0) bsum[blockIdx.x] = sm[0] + sm[1] + sm[2] + sm[3];
}

__global__ void k_scanB(const int* __restrict__ bsum, int* __restrict__ bbase, int* __restrict__ offs) {
  __shared__ int sm[256];
  int t = threadIdx.x;
  int v = bsum[t];
  sm[t] = v;
  __syncthreads();
  for (int d = 1; d < 256; d <<= 1) {
    int x = (t >= d) ? sm[t - d] : 0;
    __syncthreads();
    sm[t] += x;
    __syncthreads();
  }
  bbase[t] = sm[t] - v;
  if (t == 255) offs[N_ENT] = sm[255];
}

__global__ void k_scanC(const int* __restrict__ counts, const int* __restrict__ bbase,
                        int* __restrict__ offs, int* __restrict__ cursor) {
  __shared__ int sm[256];
  int t = threadIdx.x;
  int i = blockIdx.x * CHUNK + t;
  int v = (t < CHUNK && i < N_ENT) ? counts[i] : 0;
  sm[t] = v;
  __syncthreads();
  for (int d = 1; d < 256; d <<= 1) {
    int x = (t >= d) ? sm[t - d] : 0;
    __syncthreads();
    sm[t] += x;
    __syncthreads();
  }
  if (t < CHUNK && i < N_ENT) {
    int off = bbase[blockIdx.x] + sm[t] - v;
    offs[i] = off; cursor[i] = off;
  }
}

__global__ void k_scatter(const void* tri, const float* re_att, int* cursor,
                          int2* epk, const int* misc) {
  int is64 = misc[0];
  int stride = gridDim.x * blockDim.x;
  for (int e = blockIdx.x * blockDim.x + threadIdx.x; e < N_EDGE; e += stride) {
    int s = ld_tri(tri, 3 * e + 0, is64);
    int r = ld_tri(tri, 3 * e + 1, is64);
    int d = ld_tri(tri, 3 * e + 2, is64);
    int p = atomicAdd(&cursor[s], 1);
    epk[p] = make_int2(d, __float_as_int(re_att[r]));
  }
}

__global__ void k_pre(const float* u, const float* enw, const float* rew, const float* rsp,
                      float* a, float* b, float* zmid) {
  int k = threadIdx.x;  // 64
  float aa = 0.f, bb = 0.f;
  for (int j = 0; j < 64; j++) {
    float w = enw[j * 64 + k];
    aa += u[j] * w;
    bb += u[128 + j] * w;
  }
  a[k] = aa; b[k] = bb;
  float t = 0.f;
  for (int c = 0; c < 64; c++) t += rew[k * 64 + c] * rsp[c];
  t *= u[64 + k];
  for (int o = 32; o; o >>= 1) t += __shfl_down(t, o);
  if (k == 0) *zmid = t;
}

// one wave per node; 8 lanes per edge, 16B per lane; 8 edges per VMEM instr
template <int EPI>
__global__ void __launch_bounds__(256) k_wgc(
    const unsigned short* __restrict__ xb, const float* __restrict__ W,
    const int* __restrict__ offs, const int2* __restrict__ epk,
    unsigned short* __restrict__ yb,
    const float* __restrict__ a, const float* __restrict__ b,
    float* __restrict__ zsrc, float* __restrict__ zdst) {
  int wid = (blockIdx.x * blockDim.x + threadIdx.x) >> 6;
  int lane = threadIdx.x & 63;
  if (wid >= N_ENT) return;
  int node = wid;
  int g = lane >> 3, c8 = (lane & 7) * 8;
  int e0 = offs[node], e1 = offs[node + 1];
  float acc[8] = {0.f, 0.f, 0.f, 0.f, 0.f, 0.f, 0.f, 0.f};
  // self row, weight 1, group 0 only
  {
    uint4 q = *(const uint4*)(xb + (size_t)node * 64 + c8);
    fma8(acc, (g == 0) ? 1.f : 0.f, q);
  }
  for (int e = e0; e < e1; e += 16) {
    int ia = e + g, ib = e + 8 + g;
    bool va = ia < e1, vb = ib < e1;
    int2 pa = epk[va ? ia : e0];
    int2 pb = epk[vb ? ib : e0];
    float wa = va ? __int_as_float(pa.y) : 0.f;
    float wb = vb ? __int_as_float(pb.y) : 0.f;
    uint4 qa = *(const uint4*)(xb + (size_t)pa.x * 64 + c8);
    uint4 qb = *(const uint4*)(xb + (size_t)pb.x * 64 + c8);
    fma8(acc, wa, qa);
    fma8(acc, wb, qb);
  }
  // sum across the 8 edge-groups (lane bits 3..5)
#pragma unroll
  for (int off = 8; off <= 32; off <<= 1)
#pragma unroll
    for (int c = 0; c < 8; c++) acc[c] += __shfl_xor(acc[c], off);
  // y = tanh(m @ W): m[k] (k = 8j+c) lives in acc[c] of lane j
  float o = 0.f;
#pragma unroll
  for (int j = 0; j < 8; j++)
#pragma unroll
    for (int c = 0; c < 8; c++)
      o += lanebc(acc[c], j) * W[(j * 8 + c) * 64 + lane];
  float yv = fast_tanh(o);
  yb[(size_t)node * 64 + lane] = f2bf(yv);
  if (EPI) {
    float za = yv * a[lane], zb = yv * b[lane];
    for (int s = 32; s; s >>= 1) { za += __shfl_down(za, s); zb += __shfl_down(zb, s); }
    if (lane == 0) { zsrc[node] = za; zdst[node] = zb; }
  }
}

// unnormalized attention aggregate + per-node partial softmax sums
__global__ void __launch_bounds__(256) k_out(
    const unsigned short* __restrict__ xb, const int* __restrict__ offs,
    const int2* __restrict__ epk, const float* __restrict__ zs,
    const float* __restrict__ zd, const float* zmid,
    float* __restrict__ out, float* __restrict__ snode) {
  int wid = (blockIdx.x * blockDim.x + threadIdx.x) >> 6;
  int lane = threadIdx.x & 63;
  if (wid >= N_ENT) return;
  int node = wid;
  int g = lane >> 3, c8 = (lane & 7) * 8;
  float zi = zs[node] + *zmid;
  float acc[8] = {0.f, 0.f, 0.f, 0.f, 0.f, 0.f, 0.f, 0.f};
  float s0 = 0.f;
  int e0 = offs[node], e1 = offs[node + 1];
  for (int e = e0; e < e1; e += 16) {
    int ia = e + g, ib = e + 8 + g;
    bool va = ia < e1, vb = ib < e1;
    int2 pa = epk[va ? ia : e0];
    int2 pb = epk[vb ? ib : e0];
    float ca = zi + zd[pa.x];
    float cb = zi + zd[pb.x];
    ca = ca >= 0.f ? ca : 0.01f * ca;
    cb = cb >= 0.f ? cb : 0.01f * cb;
    float wa = va ? __expf(ca) : 0.f;
    float wb = vb ? __expf(cb) : 0.f;
    uint4 qa = *(const uint4*)(xb + (size_t)pa.x * 64 + c8);
    uint4 qb = *(const uint4*)(xb + (size_t)pb.x * 64 + c8);
    fma8(acc, wa, qa);
    fma8(acc, wb, qb);
    s0 += wa + wb;
  }
#pragma unroll
  for (int off = 8; off <= 32; off <<= 1) {
#pragma unroll
    for (int c = 0; c < 8; c++) acc[c] += __shfl_xor(acc[c], off);
    s0 += __shfl_xor(s0, off);
  }
  // lane j (0..7) holds channels [8j, 8j+8)
  if (lane < 8) {
    float4* p = (float4*)(out + (size_t)node * 64 + lane * 8);
    p[0] = make_float4(acc[0], acc[1], acc[2], acc[3]);
    p[1] = make_float4(acc[4], acc[5], acc[6], acc[7]);
  }
  if (lane == 0) snode[node] = s0;
}

__global__ void k_red(const float* __restrict__ snode, double* zsum) {
  int stride = gridDim.x * blockDim.x;
  double s = 0.0;
  for (int i = blockIdx.x * blockDim.x + threadIdx.x; i < N_ENT; i += stride)
    s += (double)snode[i];
  for (int o = 32; o; o >>= 1) s += __shfl_down(s, o);
  __shared__ double ws_[4];
  if ((threadIdx.x & 63) == 0) ws_[threadIdx.x >> 6] = s;
  __syncthreads();
  if (threadIdx.x == 0)
    atomicAdd(zsum, ws_[0] + ws_[1] + ws_[2] + ws_[3]);
}

__global__ void k_norm(float* __restrict__ out, const double* zsum) {
  int i = blockIdx.x * blockDim.x + threadIdx.x;  // 800K quads
  if (i >= N_ENT * 16) return;
  float invZ = (float)(1.0 / *zsum);
  float4 v = ((float4*)out)[i];
  v.x *= invZ; v.y *= invZ; v.z *= invZ; v.w *= invZ;
  ((float4*)out)[i] = v;
}

extern "C" void kernel_launch(void* const* d_in, const int* in_sizes, int n_in,
                              void* d_out, int out_size, void* d_ws, size_t ws_size,
                              hipStream_t stream) {
  const float* emb   = (const float*)d_in[0];
  const float* reatt = (const float*)d_in[1];
  const float* W1    = (const float*)d_in[2];
  const float* W2    = (const float*)d_in[3];
  const float* W3    = (const float*)d_in[4];
  const float* u     = (const float*)d_in[5];
  const float* enw   = (const float*)d_in[6];
  const float* rew   = (const float*)d_in[7];
  const float* rsp   = (const float*)d_in[8];
  const void*  tri   = d_in[9];

  char* ws = (char*)d_ws;
  int*            misc   = (int*)(ws + WS_MISC);
  double*         zsum   = (double*)(ws + WS_ZSUM);
  float*          zmid   = (float*)(ws + WS_ZMID);
  float*          a      = (float*)(ws + WS_A);
  float*          b      = (float*)(ws + WS_B);
  int*            bsum   = (int*)(ws + WS_BSUM);
  int*            bbase  = (int*)(ws + WS_BBASE);
  int*            counts = (int*)(ws + WS_COUNTS);
  int*            offs   = (int*)(ws + WS_OFFS);
  int*            cursor = (int*)(ws + WS_CURSOR);
  float*          zsrc   = (float*)(ws + WS_ZSRC);
  float*          zdst   = (float*)(ws + WS_ZDST);
  float*          snode  = (float*)(ws + WS_SNODE);
  int2*           epk    = (int2*)(ws + WS_EPACK);
  unsigned short* xb0    = (unsigned short*)(ws + WS_XB0);
  unsigned short* xb1    = (unsigned short*)(ws + WS_XB1);
  float*          out    = (float*)d_out;

  k_init<<<196, 256, 0, stream>>>(tri, counts, misc, zsum);
  k_conv<<<3125, 256, 0, stream>>>(emb, xb0);
  k_hist<<<1024, 256, 0, stream>>>(tri, counts, misc);
  k_scanA<<<256, 256, 0, stream>>>(counts, bsum);
  k_scanB<<<1, 256, 0, stream>>>(bsum, bbase, offs);
  k_scanC<<<256, 256, 0, stream>>>(counts, bbase, offs, cursor);
  k_scatter<<<1024, 256, 0, stream>>>(tri, reatt, cursor, epk, misc);
  k_pre<<<1, 64, 0, stream>>>(u, enw, rew, rsp, a, b, zmid);

  int nb = (N_ENT * 64 + 255) / 256;  // 12500 blocks, 4 node-waves each
  k_wgc<0><<<nb, 256, 0, stream>>>(xb0, W1, offs, epk, xb1, nullptr, nullptr, nullptr, nullptr);
  k_wgc<0><<<nb, 256, 0, stream>>>(xb1, W2, offs, epk, xb0, nullptr, nullptr, nullptr, nullptr);
  k_wgc<1><<<nb, 256, 0, stream>>>(xb0, W3, offs, epk, xb1, a, b, zsrc, zdst);

  k_out<<<nb, 256, 0, stream>>>(xb1, offs, epk, zsrc, zdst, zmid, out, snode);
  k_red<<<196, 256, 0, stream>>>(snode, zsum);
  k_norm<<<3125, 256, 0, stream>>>(out, zsum);
}

// Round 5
// 247.245 us; speedup vs baseline: 3.0224x; 1.2129x over previous
//
#include <hip/hip_runtime.h>
#include <math.h>

#define N_ENT  50000
#define N_REL  200
#define N_EDGE 1000000
#define CHUNK  196    // ceil(N_ENT/256) for scans
#define ECH    7813   // ceil(N_EDGE/128) edge chunk for partitioned scatter
#define NRNG   6250   // N_ENT/8 node range per XCD slot

// ---- ws byte offsets ----
#define WS_MISC   0          // int is64
#define WS_ZSUM   128        // double
#define WS_ZMID   192        // float
#define WS_A      256        // float[64]
#define WS_B      512        // float[64]
#define WS_BSUM   0x000E0000 // int[256]
#define WS_BBASE  0x000F0000 // int[256]
#define WS_COUNTS 0x00100000 // int[N_ENT]
#define WS_OFFS   0x00140000 // int[N_ENT+1]
#define WS_ZSRC   0x00180000 // float[N_ENT]
#define WS_ZDST   0x001C0000 // float[N_ENT]
#define WS_SNODE  0x00200000 // float[N_ENT]
#define WS_EPK    0x00240000 // uint[N_EDGE]  sorted packed (rel<<16)|dst
#define WS_PACKED 0x00640000 // uint[N_EDGE]  unsorted packed
#define WS_SRCS   0x00A40000 // int[N_EDGE]
#define WS_RANK   0x00E40000 // int[N_EDGE]
#define WS_XB1    0x00A40000 // ushort[N_ENT*64] bf16 — aliases srcs+rank (dead after scatter)
#define WS_XB0    0x01240000 // ushort[N_ENT*64] bf16

__device__ __forceinline__ float bflo(unsigned u) { return __uint_as_float(u << 16); }
__device__ __forceinline__ float bfhi(unsigned u) { return __uint_as_float(u & 0xffff0000u); }
__device__ __forceinline__ unsigned short f2bf(float f) {  // RNE
  unsigned u = __float_as_uint(f);
  unsigned r = ((u >> 16) & 1u) + 0x7fffu;
  return (unsigned short)((u + r) >> 16);
}
__device__ __forceinline__ float lanebc(float v, int k) {
  return __uint_as_float((unsigned)__builtin_amdgcn_readlane((int)__float_as_uint(v), k));
}
__device__ __forceinline__ float fast_tanh(float x) {
  float ex = __expf(2.f * x);
  return 1.f - __fdividef(2.f, ex + 1.f);
}
__device__ __forceinline__ void fma8(float* acc, float wt, uint4 q) {
  acc[0] += wt * bflo(q.x); acc[1] += wt * bfhi(q.x);
  acc[2] += wt * bflo(q.y); acc[3] += wt * bfhi(q.y);
  acc[4] += wt * bflo(q.z); acc[5] += wt * bfhi(q.z);
  acc[6] += wt * bflo(q.w); acc[7] += wt * bfhi(q.w);
}

__global__ void k_init(const void* tri, int* counts, int* misc, double* zsum) {
  int i = blockIdx.x * blockDim.x + threadIdx.x;
  if (i < N_ENT) counts[i] = 0;
  if (blockIdx.x == 0 && threadIdx.x < 64) {
    int l = threadIdx.x;
    int z = ((const int*)tri)[2 * l + 1];
    unsigned long long m = __ballot(z == 0);
    if (l == 0) { misc[0] = (m == ~0ull) ? 1 : 0; *zsum = 0.0; }
  }
}

__global__ void k_conv(const float* __restrict__ x, unsigned short* __restrict__ xb) {
  int i = blockIdx.x * blockDim.x + threadIdx.x;   // 800K quads
  if (i >= N_ENT * 16) return;
  float4 v = ((const float4*)x)[i];
  ushort4 o;
  o.x = f2bf(v.x); o.y = f2bf(v.y); o.z = f2bf(v.z); o.w = f2bf(v.w);
  ((ushort4*)xb)[i] = o;
}

// decode tri -> srcs/packed, histogram counts, rank = pre-increment count
__global__ void k_decode(const void* tri, int* __restrict__ counts,
                         int* __restrict__ srcs, unsigned* __restrict__ packed,
                         int* __restrict__ rank, const int* misc) {
  int is64 = misc[0];
  int stride = gridDim.x * blockDim.x;
  if (is64) {
    const long long* t = (const long long*)tri;
    for (int e = blockIdx.x * blockDim.x + threadIdx.x; e < N_EDGE; e += stride) {
      int s = (int)t[3 * e], r = (int)t[3 * e + 1], d = (int)t[3 * e + 2];
      srcs[e] = s;
      packed[e] = ((unsigned)r << 16) | (unsigned)d;
      rank[e] = atomicAdd(&counts[s], 1);
    }
  } else {
    const int* t = (const int*)tri;
    for (int e = blockIdx.x * blockDim.x + threadIdx.x; e < N_EDGE; e += stride) {
      int s = t[3 * e], r = t[3 * e + 1], d = t[3 * e + 2];
      srcs[e] = s;
      packed[e] = ((unsigned)r << 16) | (unsigned)d;
      rank[e] = atomicAdd(&counts[s], 1);
    }
  }
}

__global__ void k_scanA(const int* __restrict__ counts, int* __restrict__ bsum) {
  __shared__ int sm[4];
  int t = threadIdx.x;
  int i = blockIdx.x * CHUNK + t;
  int v = (t < CHUNK && i < N_ENT) ? counts[i] : 0;
  for (int o = 32; o; o >>= 1) v += __shfl_down(v, o);
  if ((t & 63) == 0) sm[t >> 6] = v;
  __syncthreads();
  if (t == 0) bsum[blockIdx.x] = sm[0] + sm[1] + sm[2] + sm[3];
}

__global__ void k_scanB(const int* __restrict__ bsum, int* __restrict__ bbase, int* __restrict__ offs) {
  __shared__ int sm[256];
  int t = threadIdx.x;
  int v = bsum[t];
  sm[t] = v;
  __syncthreads();
  for (int d = 1; d < 256; d <<= 1) {
    int x = (t >= d) ? sm[t - d] : 0;
    __syncthreads();
    sm[t] += x;
    __syncthreads();
  }
  bbase[t] = sm[t] - v;
  if (t == 255) offs[N_ENT] = sm[255];
}

__global__ void k_scanC(const int* __restrict__ counts, const int* __restrict__ bbase,
                        int* __restrict__ offs) {
  __shared__ int sm[256];
  int t = threadIdx.x;
  int i = blockIdx.x * CHUNK + t;
  int v = (t < CHUNK && i < N_ENT) ? counts[i] : 0;
  sm[t] = v;
  __syncthreads();
  for (int d = 1; d < 256; d <<= 1) {
    int x = (t >= d) ? sm[t - d] : 0;
    __syncthreads();
    sm[t] += x;
    __syncthreads();
  }
  if (t < CHUNK && i < N_ENT)
    offs[i] = bbase[blockIdx.x] + sm[t] - v;
}

// atomic-free scatter, partitioned: block b = (chunk q = b>>3, node-range x = b&7).
// With round-robin block->XCD mapping each XCD writes only its 512KB epk slice
// (L2-resident, full-line writebacks). Correct for ANY mapping.
__global__ void k_scatter(const int* __restrict__ srcs, const int* __restrict__ rank,
                          const unsigned* __restrict__ packed, const int* __restrict__ offs,
                          unsigned* __restrict__ epk) {
  int q = blockIdx.x >> 3, x = blockIdx.x & 7;
  int lo = q * ECH, hi = lo + ECH;
  if (hi > N_EDGE) hi = N_EDGE;
  for (int e = lo + threadIdx.x; e < hi; e += 256) {
    int s = srcs[e];
    if (s / NRNG == x)
      epk[offs[s] + rank[e]] = packed[e];
  }
}

__global__ void k_pre(const float* u, const float* enw, const float* rew, const float* rsp,
                      float* a, float* b, float* zmid) {
  int k = threadIdx.x;  // 64
  float aa = 0.f, bb = 0.f;
  for (int j = 0; j < 64; j++) {
    float w = enw[j * 64 + k];
    aa += u[j] * w;
    bb += u[128 + j] * w;
  }
  a[k] = aa; b[k] = bb;
  float t = 0.f;
  for (int c = 0; c < 64; c++) t += rew[k * 64 + c] * rsp[c];
  t *= u[64 + k];
  for (int o = 32; o; o >>= 1) t += __shfl_down(t, o);
  if (k == 0) *zmid = t;
}

// one wave per node; 8 lanes per edge, 16B per lane; 8 edges per VMEM instr
template <int EPI>
__global__ void __launch_bounds__(256) k_wgc(
    const unsigned short* __restrict__ xb, const float* __restrict__ W,
    const int* __restrict__ offs, const unsigned* __restrict__ epk,
    const float* __restrict__ re_att, unsigned short* __restrict__ yb,
    const float* __restrict__ a, const float* __restrict__ b,
    float* __restrict__ zsrc, float* __restrict__ zdst) {
  __shared__ float s_att[N_REL];
  for (int t = threadIdx.x; t < N_REL; t += 256) s_att[t] = re_att[t];
  __syncthreads();
  int wid = (blockIdx.x * blockDim.x + threadIdx.x) >> 6;
  int lane = threadIdx.x & 63;
  if (wid >= N_ENT) return;
  int node = wid;
  int g = lane >> 3, c8 = (lane & 7) * 8;
  int e0 = offs[node], e1 = offs[node + 1];
  float acc[8] = {0.f, 0.f, 0.f, 0.f, 0.f, 0.f, 0.f, 0.f};
  // self row, weight 1, group 0 only
  {
    uint4 q = *(const uint4*)(xb + (size_t)node * 64 + c8);
    fma8(acc, (g == 0) ? 1.f : 0.f, q);
  }
  for (int e = e0; e < e1; e += 16) {
    int ia = e + g, ib = ia + 8;
    bool va = ia < e1, vb = ib < e1;
    unsigned pa = epk[va ? ia : e0];
    unsigned pb = epk[vb ? ib : e0];
    float wa = va ? s_att[pa >> 16] : 0.f;
    float wb = vb ? s_att[pb >> 16] : 0.f;
    uint4 qa = *(const uint4*)(xb + (size_t)(pa & 0xffffu) * 64 + c8);
    uint4 qb = *(const uint4*)(xb + (size_t)(pb & 0xffffu) * 64 + c8);
    fma8(acc, wa, qa);
    fma8(acc, wb, qb);
  }
  // sum across the 8 edge-groups (lane bits 3..5)
#pragma unroll
  for (int off = 8; off <= 32; off <<= 1)
#pragma unroll
    for (int c = 0; c < 8; c++) acc[c] += __shfl_xor(acc[c], off);
  // y = tanh(m @ W): m[k] (k = 8j+c) lives in acc[c] of lane j
  float o = 0.f;
#pragma unroll
  for (int j = 0; j < 8; j++)
#pragma unroll
    for (int c = 0; c < 8; c++)
      o += lanebc(acc[c], j) * W[(j * 8 + c) * 64 + lane];
  float yv = fast_tanh(o);
  yb[(size_t)node * 64 + lane] = f2bf(yv);
  if (EPI) {
    float za = yv * a[lane], zb = yv * b[lane];
    for (int s = 32; s; s >>= 1) { za += __shfl_down(za, s); zb += __shfl_down(zb, s); }
    if (lane == 0) { zsrc[node] = za; zdst[node] = zb; }
  }
}

// unnormalized attention aggregate + per-node partial softmax sums
__global__ void __launch_bounds__(256) k_out(
    const unsigned short* __restrict__ xb, const int* __restrict__ offs,
    const unsigned* __restrict__ epk, const float* __restrict__ zs,
    const float* __restrict__ zd, const float* zmid,
    float* __restrict__ out, float* __restrict__ snode) {
  int wid = (blockIdx.x * blockDim.x + threadIdx.x) >> 6;
  int lane = threadIdx.x & 63;
  if (wid >= N_ENT) return;
  int node = wid;
  int g = lane >> 3, c8 = (lane & 7) * 8;
  float zi = zs[node] + *zmid;
  float acc[8] = {0.f, 0.f, 0.f, 0.f, 0.f, 0.f, 0.f, 0.f};
  float s0 = 0.f;
  int e0 = offs[node], e1 = offs[node + 1];
  for (int e = e0; e < e1; e += 16) {
    int ia = e + g, ib = ia + 8;
    bool va = ia < e1, vb = ib < e1;
    unsigned pa = epk[va ? ia : e0];
    unsigned pb = epk[vb ? ib : e0];
    int da = pa & 0xffffu, db = pb & 0xffffu;
    float ca = zi + zd[da];
    float cb = zi + zd[db];
    ca = ca >= 0.f ? ca : 0.01f * ca;
    cb = cb >= 0.f ? cb : 0.01f * cb;
    float wa = va ? __expf(ca) : 0.f;
    float wb = vb ? __expf(cb) : 0.f;
    uint4 qa = *(const uint4*)(xb + (size_t)da * 64 + c8);
    uint4 qb = *(const uint4*)(xb + (size_t)db * 64 + c8);
    fma8(acc, wa, qa);
    fma8(acc, wb, qb);
    s0 += wa + wb;
  }
#pragma unroll
  for (int off = 8; off <= 32; off <<= 1) {
#pragma unroll
    for (int c = 0; c < 8; c++) acc[c] += __shfl_xor(acc[c], off);
    s0 += __shfl_xor(s0, off);
  }
  // lane j (0..7) holds channels [8j, 8j+8)
  if (lane < 8) {
    float4* p = (float4*)(out + (size_t)node * 64 + lane * 8);
    p[0] = make_float4(acc[0], acc[1], acc[2], acc[3]);
    p[1] = make_float4(acc[4], acc[5], acc[6], acc[7]);
  }
  if (lane == 0) snode[node] = s0;
}

__global__ void k_red(const float* __restrict__ snode, double* zsum) {
  int stride = gridDim.x * blockDim.x;
  double s = 0.0;
  for (int i = blockIdx.x * blockDim.x + threadIdx.x; i < N_ENT; i += stride)
    s += (double)snode[i];
  for (int o = 32; o; o >>= 1) s += __shfl_down(s, o);
  __shared__ double ws_[4];
  if ((threadIdx.x & 63) == 0) ws_[threadIdx.x >> 6] = s;
  __syncthreads();
  if (threadIdx.x == 0)
    atomicAdd(zsum, ws_[0] + ws_[1] + ws_[2] + ws_[3]);
}

__global__ void k_norm(float* __restrict__ out, const double* zsum) {
  int i = blockIdx.x * blockDim.x + threadIdx.x;  // 800K quads
  if (i >= N_ENT * 16) return;
  float invZ = (float)(1.0 / *zsum);
  float4 v = ((float4*)out)[i];
  v.x *= invZ; v.y *= invZ; v.z *= invZ; v.w *= invZ;
  ((float4*)out)[i] = v;
}

extern "C" void kernel_launch(void* const* d_in, const int* in_sizes, int n_in,
                              void* d_out, int out_size, void* d_ws, size_t ws_size,
                              hipStream_t stream) {
  const float* emb   = (const float*)d_in[0];
  const float* reatt = (const float*)d_in[1];
  const float* W1    = (const float*)d_in[2];
  const float* W2    = (const float*)d_in[3];
  const float* W3    = (const float*)d_in[4];
  const float* u     = (const float*)d_in[5];
  const float* enw   = (const float*)d_in[6];
  const float* rew   = (const float*)d_in[7];
  const float* rsp   = (const float*)d_in[8];
  const void*  tri   = d_in[9];

  char* ws = (char*)d_ws;
  int*            misc   = (int*)(ws + WS_MISC);
  double*         zsum   = (double*)(ws + WS_ZSUM);
  float*          zmid   = (float*)(ws + WS_ZMID);
  float*          a      = (float*)(ws + WS_A);
  float*          b      = (float*)(ws + WS_B);
  int*            bsum   = (int*)(ws + WS_BSUM);
  int*            bbase  = (int*)(ws + WS_BBASE);
  int*            counts = (int*)(ws + WS_COUNTS);
  int*            offs   = (int*)(ws + WS_OFFS);
  float*          zsrc   = (float*)(ws + WS_ZSRC);
  float*          zdst   = (float*)(ws + WS_ZDST);
  float*          snode  = (float*)(ws + WS_SNODE);
  unsigned*       epk    = (unsigned*)(ws + WS_EPK);
  unsigned*       packed = (unsigned*)(ws + WS_PACKED);
  int*            srcs   = (int*)(ws + WS_SRCS);
  int*            rank   = (int*)(ws + WS_RANK);
  unsigned short* xb0    = (unsigned short*)(ws + WS_XB0);
  unsigned short* xb1    = (unsigned short*)(ws + WS_XB1);  // aliases srcs/rank
  float*          out    = (float*)d_out;

  k_init<<<196, 256, 0, stream>>>(tri, counts, misc, zsum);
  k_conv<<<3125, 256, 0, stream>>>(emb, xb0);
  k_decode<<<1024, 256, 0, stream>>>(tri, counts, srcs, packed, rank, misc);
  k_scanA<<<256, 256, 0, stream>>>(counts, bsum);
  k_scanB<<<1, 256, 0, stream>>>(bsum, bbase, offs);
  k_scanC<<<256, 256, 0, stream>>>(counts, bbase, offs);
  k_scatter<<<1024, 256, 0, stream>>>(srcs, rank, packed, offs, epk);
  k_pre<<<1, 64, 0, stream>>>(u, enw, rew, rsp, a, b, zmid);

  int nb = (N_ENT * 64 + 255) / 256;  // 12500 blocks, 4 node-waves each
  k_wgc<0><<<nb, 256, 0, stream>>>(xb0, W1, offs, epk, reatt, xb1, nullptr, nullptr, nullptr, nullptr);
  k_wgc<0><<<nb, 256, 0, stream>>>(xb1, W2, offs, epk, reatt, xb0, nullptr, nullptr, nullptr, nullptr);
  k_wgc<1><<<nb, 256, 0, stream>>>(xb0, W3, offs, epk, reatt, xb1, a, b, zsrc, zdst);

  k_out<<<nb, 256, 0, stream>>>(xb1, offs, epk, zsrc, zdst, zmid, out, snode);
  k_red<<<196, 256, 0, stream>>>(snode, zsum);
  k_norm<<<3125, 256, 0, stream>>>(out, zsum);
}

// Round 6
// 243.780 us; speedup vs baseline: 3.0654x; 1.0142x over previous
//
#include <hip/hip_runtime.h>
#include <math.h>

#define N_ENT  50000
#define N_REL  200
#define N_EDGE 1000000
#define CHUNK  196    // ceil(N_ENT/256) for scans
#define ECH    7813   // ceil(N_EDGE/128) edge chunk for partitioned scatter
#define NRNG   6250   // N_ENT/8 node range per partition slot

// ---- ws byte offsets ----
#define WS_MISC   0          // int is64
#define WS_ZSUM   128        // double
#define WS_ZMID   192        // float
#define WS_AV     256        // float[64]
#define WS_BV     512        // float[64]
#define WS_BSUM   0x000E0000 // int[256]
#define WS_BBASE  0x000F0000 // int[256]
#define WS_CNT8   0x00100000 // int[8][N_ENT]  replicated counters (1.6MB)
#define WS_RBASE  0x00300000 // int[8][N_ENT]  per-replica base (1.6MB)
#define WS_TOT    0x00500000 // int[N_ENT]
#define WS_OFFS   0x00540000 // int[N_ENT+1]
#define WS_ZSRC   0x00580000 // float[N_ENT]
#define WS_ZDST   0x005C0000 // float[N_ENT]
#define WS_SNODE  0x00600000 // float[N_ENT]
#define WS_EPK    0x00640000 // uint[N_EDGE] sorted packed (rel<<16)|dst
#define WS_EA     0x00A40000 // uint[N_EDGE] (src<<16)|(rep<<13)|rank
#define WS_EB     0x00E40000 // uint[N_EDGE] unsorted packed
#define WS_XB1    0x00A40000 // ushort[N_ENT*64] — aliases EA/EB (dead after scatter)
#define WS_XB0    0x01240000 // ushort[N_ENT*64]

__device__ __forceinline__ float bflo(unsigned u) { return __uint_as_float(u << 16); }
__device__ __forceinline__ float bfhi(unsigned u) { return __uint_as_float(u & 0xffff0000u); }
__device__ __forceinline__ unsigned short f2bf(float f) {  // RNE
  unsigned u = __float_as_uint(f);
  unsigned r = ((u >> 16) & 1u) + 0x7fffu;
  return (unsigned short)((u + r) >> 16);
}
__device__ __forceinline__ float lanebc(float v, int k) {
  return __uint_as_float((unsigned)__builtin_amdgcn_readlane((int)__float_as_uint(v), k));
}
__device__ __forceinline__ float fast_tanh(float x) {
  float ex = __expf(2.f * x);
  return 1.f - __fdividef(2.f, ex + 1.f);
}
__device__ __forceinline__ void fma8(float* acc, float wt, uint4 q) {
  acc[0] += wt * bflo(q.x); acc[1] += wt * bfhi(q.x);
  acc[2] += wt * bflo(q.y); acc[3] += wt * bfhi(q.y);
  acc[4] += wt * bflo(q.z); acc[5] += wt * bfhi(q.z);
  acc[6] += wt * bflo(q.w); acc[7] += wt * bfhi(q.w);
}

__global__ void k_init(const void* tri, int* cnt8, int* misc, double* zsum) {
  int i = blockIdx.x * blockDim.x + threadIdx.x;
  if (i < 8 * N_ENT) cnt8[i] = 0;
  if (blockIdx.x == 0 && threadIdx.x < 64) {
    int l = threadIdx.x;
    int z = ((const int*)tri)[2 * l + 1];
    unsigned long long m = __ballot(z == 0);
    if (l == 0) { misc[0] = (m == ~0ull) ? 1 : 0; *zsum = 0.0; }
  }
}

__global__ void k_conv(const float* __restrict__ x, unsigned short* __restrict__ xb) {
  int i = blockIdx.x * blockDim.x + threadIdx.x;   // 800K quads
  if (i >= N_ENT * 16) return;
  float4 v = ((const float4*)x)[i];
  ushort4 o;
  o.x = f2bf(v.x); o.y = f2bf(v.y); o.z = f2bf(v.z); o.w = f2bf(v.w);
  ((ushort4*)xb)[i] = o;
}

// decode tri -> packed streams; rank via 8-replicated counters (contention /8)
__global__ void k_decode(const void* tri, int* __restrict__ cnt8,
                         unsigned* __restrict__ ea, unsigned* __restrict__ eb,
                         const int* misc) {
  int is64 = misc[0];
  int rep = blockIdx.x & 7;
  int stride = gridDim.x * blockDim.x;
  if (is64) {
    const long long* t = (const long long*)tri;
    for (int e = blockIdx.x * blockDim.x + threadIdx.x; e < N_EDGE; e += stride) {
      int s = (int)t[3 * e], r = (int)t[3 * e + 1], d = (int)t[3 * e + 2];
      int rk = atomicAdd(&cnt8[rep * N_ENT + s], 1);
      ea[e] = ((unsigned)s << 16) | ((unsigned)rep << 13) | (unsigned)rk;
      eb[e] = ((unsigned)r << 16) | (unsigned)d;
    }
  } else {
    const int* t = (const int*)tri;
    for (int e = blockIdx.x * blockDim.x + threadIdx.x; e < N_EDGE; e += stride) {
      int s = t[3 * e], r = t[3 * e + 1], d = t[3 * e + 2];
      int rk = atomicAdd(&cnt8[rep * N_ENT + s], 1);
      ea[e] = ((unsigned)s << 16) | ((unsigned)rep << 13) | (unsigned)rk;
      eb[e] = ((unsigned)r << 16) | (unsigned)d;
    }
  }
}

// totals[s] = sum_rep cnt8[rep][s]; rbase[rep][s] = prefix of earlier reps
__global__ void k_merge(const int* __restrict__ cnt8, int* __restrict__ rbase,
                        int* __restrict__ tot) {
  int s = blockIdx.x * blockDim.x + threadIdx.x;
  if (s >= N_ENT) return;
  int run = 0;
#pragma unroll
  for (int rep = 0; rep < 8; rep++) {
    rbase[rep * N_ENT + s] = run;
    run += cnt8[rep * N_ENT + s];
  }
  tot[s] = run;
}

__global__ void k_scanA(const int* __restrict__ counts, int* __restrict__ bsum) {
  __shared__ int sm[4];
  int t = threadIdx.x;
  int i = blockIdx.x * CHUNK + t;
  int v = (t < CHUNK && i < N_ENT) ? counts[i] : 0;
  for (int o = 32; o; o >>= 1) v += __shfl_down(v, o);
  if ((t & 63) == 0) sm[t >> 6] = v;
  __syncthreads();
  if (t == 0) bsum[blockIdx.x] = sm[0] + sm[1] + sm[2] + sm[3];
}

__global__ void k_scanB(const int* __restrict__ bsum, int* __restrict__ bbase, int* __restrict__ offs) {
  __shared__ int sm[256];
  int t = threadIdx.x;
  int v = bsum[t];
  sm[t] = v;
  __syncthreads();
  for (int d = 1; d < 256; d <<= 1) {
    int x = (t >= d) ? sm[t - d] : 0;
    __syncthreads();
    sm[t] += x;
    __syncthreads();
  }
  bbase[t] = sm[t] - v;
  if (t == 255) offs[N_ENT] = sm[255];
}

__global__ void k_scanC(const int* __restrict__ counts, const int* __restrict__ bbase,
                        int* __restrict__ offs) {
  __shared__ int sm[256];
  int t = threadIdx.x;
  int i = blockIdx.x * CHUNK + t;
  int v = (t < CHUNK && i < N_ENT) ? counts[i] : 0;
  sm[t] = v;
  __syncthreads();
  for (int d = 1; d < 256; d <<= 1) {
    int x = (t >= d) ? sm[t - d] : 0;
    __syncthreads();
    sm[t] += x;
    __syncthreads();
  }
  if (t < CHUNK && i < N_ENT)
    offs[i] = bbase[blockIdx.x] + sm[t] - v;
}

// atomic-free scatter, 8-way src-partitioned (writes stay L2-local per XCD slot)
__global__ void k_scatter(const unsigned* __restrict__ ea, const unsigned* __restrict__ eb,
                          const int* __restrict__ offs, const int* __restrict__ rbase,
                          unsigned* __restrict__ epk) {
  int q = blockIdx.x >> 3, x = blockIdx.x & 7;
  int lo = q * ECH, hi = lo + ECH;
  if (hi > N_EDGE) hi = N_EDGE;
  for (int e = lo + threadIdx.x; e < hi; e += 256) {
    unsigned a = ea[e];
    int s = a >> 16;
    if (s / NRNG == x) {
      int rep = (a >> 13) & 7;
      int rk = a & 8191;
      epk[offs[s] + rbase[rep * N_ENT + s] + rk] = eb[e];
    }
  }
}

__global__ void k_pre(const float* u, const float* enw, const float* rew, const float* rsp,
                      float* a, float* b, float* zmid) {
  int k = threadIdx.x;  // 64
  float aa = 0.f, bb = 0.f;
  for (int j = 0; j < 64; j++) {
    float w = enw[j * 64 + k];
    aa += u[j] * w;
    bb += u[128 + j] * w;
  }
  a[k] = aa; b[k] = bb;
  float t = 0.f;
  for (int c = 0; c < 64; c++) t += rew[k * 64 + c] * rsp[c];
  t *= u[64 + k];
  for (int o = 32; o; o >>= 1) t += __shfl_down(t, o);
  if (k == 0) *zmid = t;
}

// one wave per node; 8 lanes per edge, 16B per lane; 8 edges per VMEM instr
template <int EPI>
__global__ void __launch_bounds__(256) k_wgc(
    const unsigned short* __restrict__ xb, const float* __restrict__ W,
    const int* __restrict__ offs, const unsigned* __restrict__ epk,
    const float* __restrict__ re_att, unsigned short* __restrict__ yb,
    const float* __restrict__ a, const float* __restrict__ b,
    float* __restrict__ zsrc, float* __restrict__ zdst) {
  __shared__ float s_att[N_REL];
  for (int t = threadIdx.x; t < N_REL; t += 256) s_att[t] = re_att[t];
  __syncthreads();
  int wid = (blockIdx.x * blockDim.x + threadIdx.x) >> 6;
  int lane = threadIdx.x & 63;
  if (wid >= N_ENT) return;
  int node = wid;
  int g = lane >> 3, c8 = (lane & 7) * 8;
  int e0 = offs[node], e1 = offs[node + 1];
  float acc[8] = {0.f, 0.f, 0.f, 0.f, 0.f, 0.f, 0.f, 0.f};
  {
    uint4 q = *(const uint4*)(xb + (size_t)node * 64 + c8);
    fma8(acc, (g == 0) ? 1.f : 0.f, q);
  }
  for (int e = e0; e < e1; e += 16) {
    int ia = e + g, ib = ia + 8;
    bool va = ia < e1, vb = ib < e1;
    unsigned pa = epk[va ? ia : e0];
    unsigned pb = epk[vb ? ib : e0];
    float wa = va ? s_att[pa >> 16] : 0.f;
    float wb = vb ? s_att[pb >> 16] : 0.f;
    uint4 qa = *(const uint4*)(xb + (size_t)(pa & 0xffffu) * 64 + c8);
    uint4 qb = *(const uint4*)(xb + (size_t)(pb & 0xffffu) * 64 + c8);
    fma8(acc, wa, qa);
    fma8(acc, wb, qb);
  }
#pragma unroll
  for (int off = 8; off <= 32; off <<= 1)
#pragma unroll
    for (int c = 0; c < 8; c++) acc[c] += __shfl_xor(acc[c], off);
  float o = 0.f;
#pragma unroll
  for (int j = 0; j < 8; j++)
#pragma unroll
    for (int c = 0; c < 8; c++)
      o += lanebc(acc[c], j) * W[(j * 8 + c) * 64 + lane];
  float yv = fast_tanh(o);
  yb[(size_t)node * 64 + lane] = f2bf(yv);
  if (EPI) {
    float za = yv * a[lane], zb = yv * b[lane];
    for (int s = 32; s; s >>= 1) { za += __shfl_down(za, s); zb += __shfl_down(zb, s); }
    if (lane == 0) { zsrc[node] = za; zdst[node] = zb; }
  }
}

// unnormalized attention aggregate + per-node partial softmax sums
__global__ void __launch_bounds__(256) k_out(
    const unsigned short* __restrict__ xb, const int* __restrict__ offs,
    const unsigned* __restrict__ epk, const float* __restrict__ zs,
    const float* __restrict__ zd, const float* zmid,
    float* __restrict__ out, float* __restrict__ snode) {
  int wid = (blockIdx.x * blockDim.x + threadIdx.x) >> 6;
  int lane = threadIdx.x & 63;
  if (wid >= N_ENT) return;
  int node = wid;
  int g = lane >> 3, c8 = (lane & 7) * 8;
  float zi = zs[node] + *zmid;
  float acc[8] = {0.f, 0.f, 0.f, 0.f, 0.f, 0.f, 0.f, 0.f};
  float s0 = 0.f;
  int e0 = offs[node], e1 = offs[node + 1];
  for (int e = e0; e < e1; e += 16) {
    int ia = e + g, ib = ia + 8;
    bool va = ia < e1, vb = ib < e1;
    unsigned pa = epk[va ? ia : e0];
    unsigned pb = epk[vb ? ib : e0];
    int da = pa & 0xffffu, db = pb & 0xffffu;
    float ca = zi + zd[da];
    float cb = zi + zd[db];
    ca = ca >= 0.f ? ca : 0.01f * ca;
    cb = cb >= 0.f ? cb : 0.01f * cb;
    float wa = va ? __expf(ca) : 0.f;
    float wb = vb ? __expf(cb) : 0.f;
    uint4 qa = *(const uint4*)(xb + (size_t)da * 64 + c8);
    uint4 qb = *(const uint4*)(xb + (size_t)db * 64 + c8);
    fma8(acc, wa, qa);
    fma8(acc, wb, qb);
    s0 += wa + wb;
  }
#pragma unroll
  for (int off = 8; off <= 32; off <<= 1) {
#pragma unroll
    for (int c = 0; c < 8; c++) acc[c] += __shfl_xor(acc[c], off);
    s0 += __shfl_xor(s0, off);
  }
  if (lane < 8) {
    float4* p = (float4*)(out + (size_t)node * 64 + lane * 8);
    p[0] = make_float4(acc[0], acc[1], acc[2], acc[3]);
    p[1] = make_float4(acc[4], acc[5], acc[6], acc[7]);
  }
  if (lane == 0) snode[node] = s0;
}

__global__ void k_red(const float* __restrict__ snode, double* zsum) {
  int stride = gridDim.x * blockDim.x;
  double s = 0.0;
  for (int i = blockIdx.x * blockDim.x + threadIdx.x; i < N_ENT; i += stride)
    s += (double)snode[i];
  for (int o = 32; o; o >>= 1) s += __shfl_down(s, o);
  __shared__ double ws_[4];
  if ((threadIdx.x & 63) == 0) ws_[threadIdx.x >> 6] = s;
  __syncthreads();
  if (threadIdx.x == 0)
    atomicAdd(zsum, ws_[0] + ws_[1] + ws_[2] + ws_[3]);
}

__global__ void k_norm(float* __restrict__ out, const double* zsum) {
  int i = blockIdx.x * blockDim.x + threadIdx.x;  // 800K quads
  if (i >= N_ENT * 16) return;
  float invZ = (float)(1.0 / *zsum);
  float4 v = ((float4*)out)[i];
  v.x *= invZ; v.y *= invZ; v.z *= invZ; v.w *= invZ;
  ((float4*)out)[i] = v;
}

extern "C" void kernel_launch(void* const* d_in, const int* in_sizes, int n_in,
                              void* d_out, int out_size, void* d_ws, size_t ws_size,
                              hipStream_t stream) {
  const float* emb   = (const float*)d_in[0];
  const float* reatt = (const float*)d_in[1];
  const float* W1    = (const float*)d_in[2];
  const float* W2    = (const float*)d_in[3];
  const float* W3    = (const float*)d_in[4];
  const float* u     = (const float*)d_in[5];
  const float* enw   = (const float*)d_in[6];
  const float* rew   = (const float*)d_in[7];
  const float* rsp   = (const float*)d_in[8];
  const void*  tri   = d_in[9];

  char* ws = (char*)d_ws;
  int*            misc   = (int*)(ws + WS_MISC);
  double*         zsum   = (double*)(ws + WS_ZSUM);
  float*          zmid   = (float*)(ws + WS_ZMID);
  float*          av     = (float*)(ws + WS_AV);
  float*          bv     = (float*)(ws + WS_BV);
  int*            bsum   = (int*)(ws + WS_BSUM);
  int*            bbase  = (int*)(ws + WS_BBASE);
  int*            cnt8   = (int*)(ws + WS_CNT8);
  int*            rbase  = (int*)(ws + WS_RBASE);
  int*            tot    = (int*)(ws + WS_TOT);
  int*            offs   = (int*)(ws + WS_OFFS);
  float*          zsrc   = (float*)(ws + WS_ZSRC);
  float*          zdst   = (float*)(ws + WS_ZDST);
  float*          snode  = (float*)(ws + WS_SNODE);
  unsigned*       epk    = (unsigned*)(ws + WS_EPK);
  unsigned*       ea     = (unsigned*)(ws + WS_EA);
  unsigned*       eb     = (unsigned*)(ws + WS_EB);
  unsigned short* xb0    = (unsigned short*)(ws + WS_XB0);
  unsigned short* xb1    = (unsigned short*)(ws + WS_XB1);  // aliases ea/eb
  float*          out    = (float*)d_out;

  k_init<<<1563, 256, 0, stream>>>(tri, cnt8, misc, zsum);
  k_conv<<<3125, 256, 0, stream>>>(emb, xb0);
  k_decode<<<4096, 256, 0, stream>>>(tri, cnt8, ea, eb, misc);
  k_merge<<<196, 256, 0, stream>>>(cnt8, rbase, tot);
  k_scanA<<<256, 256, 0, stream>>>(tot, bsum);
  k_scanB<<<1, 256, 0, stream>>>(bsum, bbase, offs);
  k_scanC<<<256, 256, 0, stream>>>(tot, bbase, offs);
  k_scatter<<<1024, 256, 0, stream>>>(ea, eb, offs, rbase, epk);
  k_pre<<<1, 64, 0, stream>>>(u, enw, rew, rsp, av, bv, zmid);

  int nb = (N_ENT * 64 + 255) / 256;  // 12500 blocks, 4 node-waves each
  k_wgc<0><<<nb, 256, 0, stream>>>(xb0, W1, offs, epk, reatt, xb1, nullptr, nullptr, nullptr, nullptr);
  k_wgc<0><<<nb, 256, 0, stream>>>(xb1, W2, offs, epk, reatt, xb0, nullptr, nullptr, nullptr, nullptr);
  k_wgc<1><<<nb, 256, 0, stream>>>(xb0, W3, offs, epk, reatt, xb1, av, bv, zsrc, zdst);

  k_out<<<nb, 256, 0, stream>>>(xb1, offs, epk, zsrc, zdst, zmid, out, snode);
  k_red<<<196, 256, 0, stream>>>(snode, zsum);
  k_norm<<<3125, 256, 0, stream>>>(out, zsum);
}